// Round 12
// baseline (657.269 us; speedup 1.0000x reference)
//
#include <hip/hip_runtime.h>

// Micromagnetic LLG + RK4, 128x128 grid, 256 signal steps.
// Exact simplifications (verified R0-R9):
//  - 100 relaxation steps are a bit-exact no-op => m0 = y-hat, m0_z = 0.
//  - probe value = mz_new * Msat.
//
// R11 = R7/R9 proven multi-wave structure (256 blocks x 576 thr, K=2,
// halo-8, EXT=24, 128 epochs, Chebyshev gates == R7 bit-exact algebra)
// + de-serialized exchange:
//  1. per-thread partial-order sync: each ring thread polls ONLY the
//     flag of the block owning its cell, then issues its own load
//     (replaces 8-lane serial poll + barrier; loads from early
//     neighbors overlap late ones).
//  2. 12-byte packed exchange: ws = float3[2][NPLANE]; ring load is one
//     global_load_dwordx3 sc1 (waitcnt fused in the same asm so the use
//     can't be hoisted); publish is one global_store_dwordx3 sc1.
//  R10 lesson baked in: asm VMEM is compiler-untracked, so an explicit
//  uniform s_waitcnt vmcnt(0) precedes the k==7 barrier -- every wave
//  drains its publishes BEFORE any wave can post the flag. (R10's
//  single-wave barrier elision dropped this drain => stale halos.)
//
// Exchange protocol proven R3-R9: agent-scope coherent (sc1) data ops +
// relaxed agent flags; double-buffered planes bound neighbor skew to 1
// epoch; ws 0xAA poison = negative flag => safe spin.

#define GNX 128
#define NPLANE (GNX*GNX)
#define T_STEPS 256
#define NEPOCH 128

constexpr int NBS   = 16;              // 16x16 blocks of 8x8 interior
constexpr int NBLK  = 256;
constexpr int HALO  = 8;
constexpr int EXT   = 24;              // 8 + 2*8
constexpr int NTHR  = EXT*EXT;         // 576 = 9 waves
constexpr int FSTR  = 32;              // flag stride per block (ints)

constexpr float F_H    = (float)(175950000000.0 * 1e-13);            // GAMMA*DT
constexpr float F_H6   = (float)(175950000000.0 * 1e-13 / 6.0);
constexpr float F_IDX2 = (float)(1.0 / (5e-09 * 5e-09));
constexpr float F_2A   = (float)(2.0 * 1.3e-11);
constexpr float F_NMU0 = (float)(-(4e-07 * 3.14159265358979323846));
constexpr float F_CSOT = 0.001f;
constexpr float F_ALPHA= 0.02f;
constexpr float F_CLLG = (float)(-(1.0 / (1.0 + 0.02*0.02)));

typedef float vf3 __attribute__((ext_vector_type(3)));

struct V3 { float x, y, z; };

__device__ __forceinline__ int ld_flag(const int* p) {
    return __hip_atomic_load(p, __ATOMIC_RELAXED, __HIP_MEMORY_SCOPE_AGENT);
}
__device__ __forceinline__ void st_flag(int* p, int v) {
    __hip_atomic_store(p, v, __ATOMIC_RELAXED, __HIP_MEMORY_SCOPE_AGENT);
}
// coherent 12B load; waitcnt fused in the SAME asm so the consumer of the
// output register cannot be scheduled before the data arrives.
__device__ __forceinline__ vf3 ld12_coh(const float* p) {
    vf3 v;
    asm volatile("global_load_dwordx3 %0, %1, off sc1\n\t"
                 "s_waitcnt vmcnt(0)"
                 : "=v"(v) : "v"(p) : "memory");
    return v;
}
__device__ __forceinline__ void st12_coh(float* p, vf3 v) {
    asm volatile("global_store_dwordx3 %0, %1, off sc1"
                 :: "v"(p), "v"(v) : "memory");
}

__device__ __forceinline__ V3 torque_llg(
    float mx, float my, float mz,
    float sux, float suy, float suz,
    float bx, float by, float bz, float cex, float dmg)
{
    const float lx = (sux - 4.0f*mx) * F_IDX2;
    const float ly = (suy - 4.0f*my) * F_IDX2;
    const float lz = (suz - 4.0f*mz) * F_IDX2;
    const float bex = bx + cex*lx;
    const float bey = by + cex*ly;
    const float bez = (bz + cex*lz) + dmg*mz;
    const float ax = my*bez - mz*bey;
    const float ay = mz*bex - mx*bez;
    const float az = mx*bey - my*bex;
    const float cx = my*az - mz*ay;
    const float cy = mz*ax - mx*az;
    const float cz = mx*ay - my*ax;
    // sot = C_SOT * (m x (m x p)), p=(0,1,0)
    const float sx = my*mx;
    const float sy = mz*(-mz) - mx*mx;
    const float sz = my*mz;
    V3 t;
    t.x = F_CLLG*(ax + F_ALPHA*cx) + F_CSOT*sx;
    t.y = F_CLLG*(ay + F_ALPHA*cy) + F_CSOT*sy;
    t.z = F_CLLG*(az + F_ALPHA*cz) + F_CSOT*sz;
    return t;
}

__global__ __launch_bounds__(NTHR, 1) void mm_persist(
    const float* __restrict__ signal, const float* __restrict__ B_ext,
    const float* __restrict__ Msat, const int* __restrict__ src_idx,
    const int* __restrict__ probe_idx, float* __restrict__ out,
    float* __restrict__ ws)
{
    __shared__ float4 tri[3][NTHR];     // [0]=base/m_mid plane, [1],[2]=trials
    __shared__ float  sgl[2*T_STEPS];   // full signal

    const int tid = threadIdx.x;
    const int bid = blockIdx.x;
    const int br = bid >> 4, bc = bid & 15;
    const int r0 = br*8, c0 = bc*8;

    // ws layout: float m3[2][NPLANE][3] | int flags[NBLK*FSTR]
    float* ws3 = ws;
    int* flags = (int*)(ws + (size_t)2*NPLANE*3);

    // ---- fixed per-thread geometry ----
    const int er = tid / EXT, ec = tid - (tid/EXT)*EXT;
    const int gr = r0 - HALO + er, gc = c0 - HALO + ec;
    const bool in_grid = ((unsigned)gr < (unsigned)GNX) && ((unsigned)gc < (unsigned)GNX);
    const int grc = min(max(gr, 0), GNX-1), gcc = min(max(gc, 0), GNX-1);
    const int gidx = grc*GNX + gcc;
    // Chebyshev distance to the 8x8 interior square [HALO, HALO+8)
    const int drr = max(max(HALO - er, er - (HALO+7)), 0);
    const int dcc = max(max(HALO - ec, ec - (HALO+7)), 0);
    const int C = in_grid ? max(drr, dcc) : 99;  // active@k iff C<=7-k
    const bool is_ring = (C >= 1) && (C <= 8);
    const int owner = ((gr >> 3) << 4) | (gc >> 3);   // block owning my cell

    // neighbor LDS indices, grid-edge clamp baked in
    const int iU = (((gr == 0)     ? er : er-1) * EXT) + ec;
    const int iD = (((gr == GNX-1) ? er : er+1) * EXT) + ec;
    const int iL = (er * EXT) + ((gc == 0)     ? ec : ec-1);
    const int iR = (er * EXT) + ((gc == GNX-1) ? ec : ec+1);

    // static per-cell fields in registers
    const float bxr = B_ext[0*NPLANE + gidx];
    const float byr = B_ext[1*NPLANE + gidx];
    const float bzr = B_ext[2*NPLANE + gidx];
    const float ms  = Msat[gidx];
    const float cex = F_2A / ms;
    const float dmg = F_NMU0 * ms;
    const bool isS0 = in_grid && (gr == src_idx[0]) && (gc == src_idx[1]);
    const bool isS1 = in_grid && (gr == src_idx[2]) && (gc == src_idx[3]);
    int pj = -1;
    if (C == 0) {
        #pragma unroll
        for (int j = 0; j < 4; ++j)
            if (gr == probe_idx[2*j] && gc == probe_idx[2*j+1]) pj = j;
    }

    // ---- init: m0 = y-hat everywhere; stage signal ----
    if (tid < 2*T_STEPS) sgl[tid] = signal[tid];
    tri[0][tid] = make_float4(0.f, 1.f, 0.f, 0.f);
    float bmx = 0.f, bmy = 1.f, bmz = 0.f;    // own base m
    float kx = 0.f, ky = 0.f, kz = 0.f;       // RK4 accumulator (registers)
    float twx = 0.f, twy = 1.f, twz = 0.f;    // own last trial
    __syncthreads();

    for (int e = 0; e < NEPOCH; ++e) {
        const int cb = e & 1, pb = cb ^ 1;

        if (e > 0) {
            // partial-order sync: each ring thread polls ONLY its owner's
            // flag, then immediately loads its cell (12B coherent).
            if (is_ring) {
                const int* fp = flags + owner*FSTR;
                while (ld_flag(fp) < e) {}
                const vf3 v = ld12_coh(ws3 + ((size_t)pb*NPLANE + gidx)*3);
                bmx = v.x; bmy = v.y; bmz = v.z;
                tri[0][tid] = make_float4(v.x, v.y, v.z, 0.f);
            }
        }
        const float sA0 = sgl[4*e+0], sA1 = sgl[4*e+1];
        const float sB0 = sgl[4*e+2], sB1 = sgl[4*e+3];
        kx = 0.f; ky = 0.f; kz = 0.f;   // insurance; gated sums reset at use
        __syncthreads();   // all ring cells in LDS before substep 0

        // ---- 8 RK4 substeps (2 fused steps), Chebyshev regions 7..0 ----
        #pragma unroll
        for (int k = 0; k < 8; ++k) {
            const int kk = k & 3;
            const float wk = (kk == 1 || kk == 2) ? 2.0f : 1.0f;
            const float cc = (kk == 2) ? 1.0f : 0.5f;
            const float sg0 = (k < 4) ? sA0 : sB0;
            const float sg1 = (k < 4) ? sA1 : sB1;
            const int rs  = (kk == 0) ? 0 : ((kk == 2) ? 2 : 1);
            const int wsb = (kk == 1) ? 2 : 1;

            if (C <= 7 - k) {             // activity gate (== R7 dd>k)
                const float4 nu = tri[rs][iU];
                const float4 nd = tri[rs][iD];
                const float4 nl = tri[rs][iL];
                const float4 nr = tri[rs][iR];
                float mx, my, mz;
                if (kk == 0) { mx = bmx; my = bmy; mz = bmz; }
                else         { mx = twx; my = twy; mz = twz; }
                const float sux = ((nd.x + nu.x) + nr.x) + nl.x;
                const float suy = ((nd.y + nu.y) + nr.y) + nl.y;
                const float suz = ((nd.z + nu.z) + nr.z) + nl.z;

                float bz = isS0 ? sg0 : bzr;
                bz = isS1 ? sg1 : bz;

                const V3 tq = torque_llg(mx, my, mz, sux, suy, suz,
                                         bxr, byr, bz, cex, dmg);
                // accumulate only if consumed at this sum's mid/final (k|3)
                if (C <= 7 - (k | 3)) {
                    kx += wk*tq.x; ky += wk*tq.y; kz += wk*tq.z;
                }

                if (kk < 3) {
                    twx = bmx + (F_H*tq.x)*cc;
                    twy = bmy + (F_H*tq.y)*cc;
                    twz = bmz + (F_H*tq.z)*cc;
                    tri[wsb][tid] = make_float4(twx, twy, twz, 0.f);
                } else {
                    // mid (k==3) / final (k==7): advance base by H/6 * ka
                    bmx += F_H6*kx; bmy += F_H6*ky; bmz += F_H6*kz;
                    kx = 0.f; ky = 0.f; kz = 0.f;
                    tri[0][tid] = make_float4(bmx, bmy, bmz, 0.f);
                    if (C == 0) {        // interior: publish at k==7, probes
                        if (k == 7) {
                            vf3 v; v.x = bmx; v.y = bmy; v.z = bmz;
                            st12_coh(ws3 + ((size_t)cb*NPLANE + gidx)*3, v);
                        }
                        if (pj >= 0) {
                            out[(2*e + (k >> 2))*4 + pj] = bmz * ms;  // m0_z==0
                        }
                    }
                }
            }
            if (k == 7) {
                // asm stores are compiler-untracked: every wave drains its
                // own publishes BEFORE arriving at the barrier, so the flag
                // post below is ordered after ALL waves' publishes. (R10 bug)
                asm volatile("s_waitcnt vmcnt(0)" ::: "memory");
            }
            __syncthreads();
        }

        if (tid == 0) st_flag(flags + bid*FSTR, e + 1);
    }
}

extern "C" void kernel_launch(void* const* d_in, const int* in_sizes, int n_in,
                              void* d_out, int out_size, void* d_ws, size_t ws_size,
                              hipStream_t stream) {
    const float* sig  = (const float*)d_in[0];
    const float* Bex  = (const float*)d_in[1];
    const float* Ms   = (const float*)d_in[2];
    const int*   srci = (const int*)d_in[3];
    const int*   prbi = (const int*)d_in[4];
    float* out = (float*)d_out;
    float* ws  = (float*)d_ws;

    void* args[] = { (void*)&sig, (void*)&Bex, (void*)&Ms,
                     (void*)&srci, (void*)&prbi, (void*)&out, (void*)&ws };
    hipLaunchCooperativeKernel((const void*)mm_persist, dim3(NBLK), dim3(NTHR),
                               args, 0, stream);
}

// Round 13
// 600.330 us; speedup vs baseline: 1.0948x; 1.0948x over previous
//
#include <hip/hip_runtime.h>

// Micromagnetic LLG + RK4, 128x128 grid, 256 signal steps.
// Exact simplifications (verified R0-R11):
//  - 100 relaxation steps are a bit-exact no-op => m0 = y-hat, m0_z = 0.
//  - probe value = mz_new * Msat.
//
// R12 = R11 structure (256 blocks x 576 thr, K=2, halo-8, EXT=24, 128
// epochs, Chebyshev gates == R7 bit-exact algebra) + TAG-EMBEDDED 16B
// EXCHANGE (flag merged into data).
//  R11 showed all flag fabrics cost the same ~3us/epoch: the chain
//  publish-drain -> barrier -> flag store -> L3 -> flag detect -> data
//  load pays TWO L3 rounds + a drain. Fix: ws = float4[2][NPLANE] with
//  .w = epoch tag. Writer: one global_store_dwordx4 sc1 per interior
//  cell carrying (x,y,z,e+1) -- fire-and-forget, no drain, no flag.
//  Reader: each ring thread spins on ITS OWN cell with dwordx4 sc1
//  loads until tag >= e. Detection = data arrival; one L3 round total.
//  Safety: aligned 16B store is a single L2/L3 transaction; double
//  buffer + skew<=1 induction (writer cannot write tag e+2 into buf[p]
//  until its neighbors published e+1, which implies they consumed e)
//  makes "tag >= e" exact. 0xAA poison reads as -3e-13 < 1 => safe spin.

#define GNX 128
#define NPLANE (GNX*GNX)
#define T_STEPS 256
#define NEPOCH 128

constexpr int NBS   = 16;              // 16x16 blocks of 8x8 interior
constexpr int NBLK  = 256;
constexpr int HALO  = 8;
constexpr int EXT   = 24;              // 8 + 2*8
constexpr int NTHR  = EXT*EXT;         // 576 = 9 waves

constexpr float F_H    = (float)(175950000000.0 * 1e-13);            // GAMMA*DT
constexpr float F_H6   = (float)(175950000000.0 * 1e-13 / 6.0);
constexpr float F_IDX2 = (float)(1.0 / (5e-09 * 5e-09));
constexpr float F_2A   = (float)(2.0 * 1.3e-11);
constexpr float F_NMU0 = (float)(-(4e-07 * 3.14159265358979323846));
constexpr float F_CSOT = 0.001f;
constexpr float F_ALPHA= 0.02f;
constexpr float F_CLLG = (float)(-(1.0 / (1.0 + 0.02*0.02)));

typedef float vf4 __attribute__((ext_vector_type(4)));

struct V3 { float x, y, z; };

// coherent 16B load; waitcnt fused in the SAME asm so the consumer of the
// output registers cannot be scheduled before the data arrives.
__device__ __forceinline__ vf4 ld16_coh(const vf4* p) {
    vf4 v;
    asm volatile("global_load_dwordx4 %0, %1, off sc1\n\t"
                 "s_waitcnt vmcnt(0)"
                 : "=v"(v) : "v"(p) : "memory");
    return v;
}
__device__ __forceinline__ void st16_coh(vf4* p, vf4 v) {
    asm volatile("global_store_dwordx4 %0, %1, off sc1"
                 :: "v"(p), "v"(v) : "memory");
}

__device__ __forceinline__ V3 torque_llg(
    float mx, float my, float mz,
    float sux, float suy, float suz,
    float bx, float by, float bz, float cex, float dmg)
{
    const float lx = (sux - 4.0f*mx) * F_IDX2;
    const float ly = (suy - 4.0f*my) * F_IDX2;
    const float lz = (suz - 4.0f*mz) * F_IDX2;
    const float bex = bx + cex*lx;
    const float bey = by + cex*ly;
    const float bez = (bz + cex*lz) + dmg*mz;
    const float ax = my*bez - mz*bey;
    const float ay = mz*bex - mx*bez;
    const float az = mx*bey - my*bex;
    const float cx = my*az - mz*ay;
    const float cy = mz*ax - mx*az;
    const float cz = mx*ay - my*ax;
    // sot = C_SOT * (m x (m x p)), p=(0,1,0)
    const float sx = my*mx;
    const float sy = mz*(-mz) - mx*mx;
    const float sz = my*mz;
    V3 t;
    t.x = F_CLLG*(ax + F_ALPHA*cx) + F_CSOT*sx;
    t.y = F_CLLG*(ay + F_ALPHA*cy) + F_CSOT*sy;
    t.z = F_CLLG*(az + F_ALPHA*cz) + F_CSOT*sz;
    return t;
}

__global__ __launch_bounds__(NTHR, 1) void mm_persist(
    const float* __restrict__ signal, const float* __restrict__ B_ext,
    const float* __restrict__ Msat, const int* __restrict__ src_idx,
    const int* __restrict__ probe_idx, float* __restrict__ out,
    float* __restrict__ ws)
{
    __shared__ float4 tri[3][NTHR];     // [0]=base/m_mid plane, [1],[2]=trials
    __shared__ float  sgl[2*T_STEPS];   // full signal

    const int tid = threadIdx.x;
    const int bid = blockIdx.x;
    const int br = bid >> 4, bc = bid & 15;
    const int r0 = br*8, c0 = bc*8;

    // ws layout: vf4 m4[2][NPLANE]  (x,y,z,epoch-tag)
    vf4* m4 = (vf4*)ws;

    // ---- fixed per-thread geometry ----
    const int er = tid / EXT, ec = tid - (tid/EXT)*EXT;
    const int gr = r0 - HALO + er, gc = c0 - HALO + ec;
    const bool in_grid = ((unsigned)gr < (unsigned)GNX) && ((unsigned)gc < (unsigned)GNX);
    const int grc = min(max(gr, 0), GNX-1), gcc = min(max(gc, 0), GNX-1);
    const int gidx = grc*GNX + gcc;
    // Chebyshev distance to the 8x8 interior square [HALO, HALO+8)
    const int drr = max(max(HALO - er, er - (HALO+7)), 0);
    const int dcc = max(max(HALO - ec, ec - (HALO+7)), 0);
    const int C = in_grid ? max(drr, dcc) : 99;  // active@k iff C<=7-k
    const bool is_ring = (C >= 1) && (C <= 8);

    // neighbor LDS indices, grid-edge clamp baked in
    const int iU = (((gr == 0)     ? er : er-1) * EXT) + ec;
    const int iD = (((gr == GNX-1) ? er : er+1) * EXT) + ec;
    const int iL = (er * EXT) + ((gc == 0)     ? ec : ec-1);
    const int iR = (er * EXT) + ((gc == GNX-1) ? ec : ec+1);

    // static per-cell fields in registers
    const float bxr = B_ext[0*NPLANE + gidx];
    const float byr = B_ext[1*NPLANE + gidx];
    const float bzr = B_ext[2*NPLANE + gidx];
    const float ms  = Msat[gidx];
    const float cex = F_2A / ms;
    const float dmg = F_NMU0 * ms;
    const bool isS0 = in_grid && (gr == src_idx[0]) && (gc == src_idx[1]);
    const bool isS1 = in_grid && (gr == src_idx[2]) && (gc == src_idx[3]);
    int pj = -1;
    if (C == 0) {
        #pragma unroll
        for (int j = 0; j < 4; ++j)
            if (gr == probe_idx[2*j] && gc == probe_idx[2*j+1]) pj = j;
    }

    // ---- init: m0 = y-hat everywhere; stage signal ----
    if (tid < 2*T_STEPS) sgl[tid] = signal[tid];
    tri[0][tid] = make_float4(0.f, 1.f, 0.f, 0.f);
    float bmx = 0.f, bmy = 1.f, bmz = 0.f;    // own base m
    float kx = 0.f, ky = 0.f, kz = 0.f;       // RK4 accumulator (registers)
    float twx = 0.f, twy = 1.f, twz = 0.f;    // own last trial
    __syncthreads();

    for (int e = 0; e < NEPOCH; ++e) {
        const int cb = e & 1, pb = cb ^ 1;

        if (e > 0) {
            // tag-poll: each ring thread spins on ITS OWN cell until the
            // owner's 16B publish (tag = e) lands. One L3 round total.
            if (is_ring) {
                vf4* p = m4 + (size_t)pb*NPLANE + gidx;
                vf4 v;
                do { v = ld16_coh(p); } while (v.w < (float)e);
                bmx = v.x; bmy = v.y; bmz = v.z;
                tri[0][tid] = make_float4(v.x, v.y, v.z, 0.f);
            }
        }
        const float sA0 = sgl[4*e+0], sA1 = sgl[4*e+1];
        const float sB0 = sgl[4*e+2], sB1 = sgl[4*e+3];
        kx = 0.f; ky = 0.f; kz = 0.f;   // insurance; gated sums reset at use
        __syncthreads();   // all ring cells in LDS before substep 0

        // ---- 8 RK4 substeps (2 fused steps), Chebyshev regions 7..0 ----
        #pragma unroll
        for (int k = 0; k < 8; ++k) {
            const int kk = k & 3;
            const float wk = (kk == 1 || kk == 2) ? 2.0f : 1.0f;
            const float cc = (kk == 2) ? 1.0f : 0.5f;
            const float sg0 = (k < 4) ? sA0 : sB0;
            const float sg1 = (k < 4) ? sA1 : sB1;
            const int rs  = (kk == 0) ? 0 : ((kk == 2) ? 2 : 1);
            const int wsb = (kk == 1) ? 2 : 1;

            if (C <= 7 - k) {             // activity gate (== R7 dd>k)
                const float4 nu = tri[rs][iU];
                const float4 nd = tri[rs][iD];
                const float4 nl = tri[rs][iL];
                const float4 nr = tri[rs][iR];
                float mx, my, mz;
                if (kk == 0) { mx = bmx; my = bmy; mz = bmz; }
                else         { mx = twx; my = twy; mz = twz; }
                const float sux = ((nd.x + nu.x) + nr.x) + nl.x;
                const float suy = ((nd.y + nu.y) + nr.y) + nl.y;
                const float suz = ((nd.z + nu.z) + nr.z) + nl.z;

                float bz = isS0 ? sg0 : bzr;
                bz = isS1 ? sg1 : bz;

                const V3 tq = torque_llg(mx, my, mz, sux, suy, suz,
                                         bxr, byr, bz, cex, dmg);
                // accumulate only if consumed at this sum's mid/final (k|3)
                if (C <= 7 - (k | 3)) {
                    kx += wk*tq.x; ky += wk*tq.y; kz += wk*tq.z;
                }

                if (kk < 3) {
                    twx = bmx + (F_H*tq.x)*cc;
                    twy = bmy + (F_H*tq.y)*cc;
                    twz = bmz + (F_H*tq.z)*cc;
                    tri[wsb][tid] = make_float4(twx, twy, twz, 0.f);
                } else {
                    // mid (k==3) / final (k==7): advance base by H/6 * ka
                    bmx += F_H6*kx; bmy += F_H6*ky; bmz += F_H6*kz;
                    kx = 0.f; ky = 0.f; kz = 0.f;
                    tri[0][tid] = make_float4(bmx, bmy, bmz, 0.f);
                    if (C == 0) {        // interior: publish at k==7, probes
                        if (k == 7) {
                            vf4 v;
                            v.x = bmx; v.y = bmy; v.z = bmz;
                            v.w = (float)(e + 1);   // tag: epoch e complete
                            st16_coh(m4 + (size_t)cb*NPLANE + gidx, v);
                        }
                        if (pj >= 0) {
                            out[(2*e + (k >> 2))*4 + pj] = bmz * ms;  // m0_z==0
                        }
                    }
                }
            }
            __syncthreads();
        }
        // no drain, no flag: readers poll the published cells directly.
    }
}

extern "C" void kernel_launch(void* const* d_in, const int* in_sizes, int n_in,
                              void* d_out, int out_size, void* d_ws, size_t ws_size,
                              hipStream_t stream) {
    const float* sig  = (const float*)d_in[0];
    const float* Bex  = (const float*)d_in[1];
    const float* Ms   = (const float*)d_in[2];
    const int*   srci = (const int*)d_in[3];
    const int*   prbi = (const int*)d_in[4];
    float* out = (float*)d_out;
    float* ws  = (float*)d_ws;

    void* args[] = { (void*)&sig, (void*)&Bex, (void*)&Ms,
                     (void*)&srci, (void*)&prbi, (void*)&out, (void*)&ws };
    hipLaunchCooperativeKernel((const void*)mm_persist, dim3(NBLK), dim3(NTHR),
                               args, 0, stream);
}